// Round 12
// baseline (564.743 us; speedup 1.0000x reference)
//
#include <hip/hip_runtime.h>
#include <hip/hip_bf16.h>
#include <math.h>

// ---------------------------------------------------------------------------
// MoE block: y = sum_topk2 w_e * FFN_e(x)  +  FFN_shared(x)
// T=4096, D=1024, H=4096, E=8, K=2.  bf16 MFMA compute.
// R12: max-TLP GEMM — 128x128 tile, BK=32, 8 waves (512 thr, wave-tile
// 64x32, acc[4][2]=32 VGPR), 32 KB dbuf LDS, launch_bounds(512,8) ->
// 4 blocks/CU = 32 waves/CU = 8 waves/SIMD (hw max). Waves/SIMD is the
// only variable that moved GEMM time across R1-R11 (1->2->4 w/SIMD gave
// 280->240->204 us); this tests the next doubling. Counted vmcnt(2),
// swapped-operand MFMA + vectorized epilogue (R11), XCD patch swizzle.
// ---------------------------------------------------------------------------

typedef unsigned short ushort_t;
typedef __attribute__((ext_vector_type(8))) __bf16 bf16x8;
typedef __attribute__((ext_vector_type(4))) float f32x4;

#define T_TOK 4096
#define DDIM  1024
#define HDIM  4096
#define NEXP  8
#define SLOT_PAD 10240           // 8192 + 8*256 pad headroom (256-aligned regions)
#define M_ALL (SLOT_PAD + T_TOK) // 14336 rows: experts then shared

// workspace layout (bytes)
#define OFF_CNT   0u             // int[8] cnt + int[8] cur
#define OFF_OFFS  64u            // int[16]
#define OFF_TIDX  256u           // int[8192]
#define OFF_TW    33024u         // float[8192]
#define OFF_SLOT  65792u         // int[8192]
#define OFF_TOK   98560u         // int[10240]
#define OFF_XALL  1048576u                        // bf16 [14336][1024] = 29,360,128
#define OFF_OUTS  OFF_XALL                        // bf16 [10240][1024] (aliases Xall)
#define OFF_WT    (OFF_XALL + 29360128u)          // bf16 [9][N][K] = 75,497,472
#define OFF_H     (OFF_WT + 75497472u)            // bf16 [14336][4096] = 117,440,512

__device__ __forceinline__ ushort_t f2b(float f) {
    __hip_bfloat16 h = __float2bfloat16(f);
    return *reinterpret_cast<ushort_t*>(&h);
}
__device__ __forceinline__ float b2f(ushort_t u) {
    __hip_bfloat16 h;
    *reinterpret_cast<ushort_t*>(&h) = u;
    return __bfloat162float(h);
}
// tanh-form GELU (max |dev| from exact erf-GELU ~3e-3; bf16-safe here)
__device__ __forceinline__ float gelu_fast(float v) {
    float u = 0.7978845608f * v * (1.0f + 0.044715f * v * v);
    float t = 1.0f - 2.0f / (__expf(2.0f * u) + 1.0f);
    return 0.5f * v * (1.0f + t);
}

// -------------------------------- gate -------------------------------------
__global__ void gate_kernel(const float* __restrict__ x, const float* __restrict__ gw,
                            int* __restrict__ tidx, float* __restrict__ tw,
                            int* __restrict__ cnt) {
    int t = blockIdx.x;
    int l = threadIdx.x;
    float acc[NEXP];
#pragma unroll
    for (int e = 0; e < NEXP; ++e) acc[e] = 0.f;
    for (int i = 0; i < DDIM / 64; ++i) {
        float xi = x[(size_t)t * DDIM + i * 64 + l];
#pragma unroll
        for (int e = 0; e < NEXP; ++e)
            acc[e] += xi * gw[e * DDIM + i * 64 + l];
    }
#pragma unroll
    for (int e = 0; e < NEXP; ++e)
        for (int off = 32; off; off >>= 1) acc[e] += __shfl_xor(acc[e], off);
    if (l == 0) {
        float m = acc[0];
#pragma unroll
        for (int e = 1; e < NEXP; ++e) m = fmaxf(m, acc[e]);
        float ex[NEXP], Z = 0.f;
#pragma unroll
        for (int e = 0; e < NEXP; ++e) { ex[e] = __expf(acc[e] - m); Z += ex[e]; }
        int b0 = 0;
#pragma unroll
        for (int e = 1; e < NEXP; ++e) if (ex[e] > ex[b0]) b0 = e;
        int b1 = (b0 == 0) ? 1 : 0;
#pragma unroll
        for (int e = 0; e < NEXP; ++e) if (e != b0 && ex[e] > ex[b1]) b1 = e;
        float inv = 1.0f / Z;
        tidx[2 * t] = b0; tidx[2 * t + 1] = b1;
        tw[2 * t] = ex[b0] * inv; tw[2 * t + 1] = ex[b1] * inv;
        atomicAdd(&cnt[b0], 1);
        atomicAdd(&cnt[b1], 1);
    }
}

// ------------------------- assign (+ offs, merged) -------------------------
// Every block recomputes the 8-entry padded prefix from cnt (reads only);
// block 0 thread 0 publishes offs. Slot order within an expert is
// atomic-race-dependent, but the OUTPUT is permutation-invariant.
__global__ void assign_kernel(const int* __restrict__ tidx, const int* __restrict__ cnt,
                              int* __restrict__ cur, int* __restrict__ offs,
                              int* __restrict__ slot_of, int* __restrict__ tok_of) {
    int off[NEXP + 1];
    off[0] = 0;
#pragma unroll
    for (int e = 0; e < NEXP; ++e) off[e + 1] = off[e] + ((cnt[e] + 255) & ~255);
    int i = blockIdx.x * 256 + threadIdx.x;
    if (i == 0) {
#pragma unroll
        for (int e = 0; e <= NEXP; ++e) offs[e] = off[e];
    }
    if (i >= 2 * T_TOK) return;
    int e = tidx[i];
    int s = off[e] + atomicAdd(&cur[e], 1);
    slot_of[i] = s;
    tok_of[s] = i >> 1;
}

// ------------------------------- build X -----------------------------------
// Pad slots detected from offs+cnt (local index >= cnt[e]) — no tok_of init.
__global__ void build_x(const float* __restrict__ x, const int* __restrict__ tok_of,
                        const int* __restrict__ offs, const int* __restrict__ cnt,
                        ushort_t* __restrict__ Xall) {
    int b = blockIdx.x;
    int k = threadIdx.x * 4;
    int t;
    if (b < SLOT_PAD) {
        if (b >= offs[NEXP]) return;
        int e = 0;
        while (offs[e + 1] <= b) e++;
        t = (b - offs[e] < cnt[e]) ? tok_of[b] : -1;
    } else {
        t = b - SLOT_PAD;
    }
    float4 v = make_float4(0.f, 0.f, 0.f, 0.f);
    if (t >= 0) v = *(const float4*)(x + (size_t)t * DDIM + k);
    ushort_t* p = Xall + (size_t)b * DDIM + k;
    p[0] = f2b(v.x); p[1] = f2b(v.y); p[2] = f2b(v.z); p[3] = f2b(v.w);
}

// --------------------------- transpose + cvt (9 experts) -------------------
// in [K][N] fp32 -> out [N][K] bf16 ; grid (K/64, N/64, 9); z==8 -> shared.
__global__ void transpose_cvt9(const float* __restrict__ w, const float* __restrict__ sw,
                               ushort_t* __restrict__ out, int K, int N) {
    __shared__ float t[64][65];
    int z = blockIdx.z;
    const float* in = (z < NEXP) ? w + (size_t)z * K * N : sw;
    out += (size_t)z * K * N;
    int k0 = blockIdx.x * 64, n0 = blockIdx.y * 64;
    int c = threadIdx.x & 63, r4 = threadIdx.x >> 6;
#pragma unroll
    for (int i = 0; i < 16; ++i) {
        int r = r4 + i * 4;
        t[r][c] = in[(size_t)(k0 + r) * N + n0 + c];
    }
    __syncthreads();
#pragma unroll
    for (int i = 0; i < 16; ++i) {
        int r = r4 + i * 4;
        out[(size_t)(n0 + r) * K + k0 + c] = f2b(t[c][r]);
    }
}

// ------------------------------ GEMM (bt) ----------------------------------
// C[M,N] = act(A[M,K] @ Bt[e][N,K]^T + bias), rows grouped by expert
// (256-aligned), expert 8 = shared. 128x128 tile, BK=32, 8 waves (512 thr,
// 2Mx4N wave grid, wave-tile 64x32, acc[4][2]), mfma(B,A) swapped operands.
// LDS: As/Bs[2][128*32] = 32 KB -> 4 blocks/CU (32 waves/CU, 8/SIMD max).
// Swizzle (rows of 32 elems = 4 chunks): chunk c = q ^ ((row>>1)&3), same
// involution on stage (pre-swizzled source) and read; reads 2-way = free.
// Sync: stage(t+1) [2 loads/thr] -> vmcnt(2) -> s_barrier -> compute ->
// s_barrier (R7-proven counted form; never vmcnt(0) in-loop).
template <bool ACT_GELU, bool FFN2>
__global__ __launch_bounds__(512, 8) void gemm_moe(
    const ushort_t* __restrict__ A, const ushort_t* __restrict__ WtBase,
    const float* __restrict__ bExp, const float* __restrict__ bSh,
    ushort_t* __restrict__ Cb, float* __restrict__ Cf,
    const int* __restrict__ offs, int N, int K) {
    // ---- per-XCD patch swizzle (bijective; NM%4==0, NN%2==0) ----
    int NMt = gridDim.x, NNt = gridDim.y;
    int flat = blockIdx.y * NMt + blockIdx.x;
    int xcd = flat & 7, rank = flat >> 3;
    int PM = NMt >> 2;                    // patch rows (28)
    int PN = NNt >> 1;                    // patch cols (16 or 4)
    int pm = xcd >> 1, pn = xcd & 1;      // 4 x 2 patch grid
    int mi = pm * PM + rank / PN;
    int ni = pn * PN + rank % PN;
    int m0 = mi * 128, n0 = ni * 128;

    int e;
    if (m0 >= SLOT_PAD) {
        e = NEXP;                        // shared region
    } else {
        if (m0 >= offs[NEXP]) return;    // dead pad zone (before any barrier)
        e = 0;
        while (offs[e + 1] <= m0) e++;
    }
    const ushort_t* Bt = WtBase + (size_t)e * N * K;
    const float* bias = (e == NEXP) ? bSh : bExp + (size_t)e * N;

    __shared__ ushort_t As[2][128 * 32];   // 2 x 8 KB
    __shared__ ushort_t Bs[2][128 * 32];   // 2 x 8 KB

    int tid = threadIdx.x;
    int lane = tid & 63, wid = tid >> 6;   // 8 waves
    int wm = wid >> 2, wn = wid & 3;       // 2M x 4N wave grid
    int q = lane >> 4, lr = lane & 15;

    // staging: per operand 512 16B-chunks, 1/thread. L = tid; row = L>>2,
    // stored chunk = L&3, source chunk = (L&3) ^ ((row>>1)&3).
    int srow = tid >> 2;
    int su = ((tid & 3) ^ ((srow >> 1) & 3)) * 8;
    size_t Aoff = (size_t)(m0 + srow) * K + su;
    size_t Boff = (size_t)(n0 + srow) * K + su;
    int ldsOff = tid * 8;                  // ushort elements

    f32x4 acc[4][2];
#pragma unroll
    for (int i = 0; i < 4; ++i)
#pragma unroll
        for (int j = 0; j < 2; ++j) acc[i][j] = (f32x4)(0.f);

    auto stage = [&](int kb, int buf) {    // 2 loads per thread
        __builtin_amdgcn_global_load_lds(
            (const __attribute__((address_space(1))) void*)(A + Aoff + kb),
            (__attribute__((address_space(3))) void*)(&As[buf][ldsOff]), 16, 0, 0);
        __builtin_amdgcn_global_load_lds(
            (const __attribute__((address_space(1))) void*)(Bt + Boff + kb),
            (__attribute__((address_space(3))) void*)(&Bs[buf][ldsOff]), 16, 0, 0);
    };
    auto compute = [&](int buf) {
        bf16x8 af[4], bfr[2];
#pragma unroll
        for (int j = 0; j < 2; ++j) {
            int r = wn * 32 + j * 16 + lr;
            int c = q ^ ((r >> 1) & 3);
            bfr[j] = *(const bf16x8*)(&Bs[buf][r * 32 + c * 8]);
        }
#pragma unroll
        for (int i = 0; i < 4; ++i) {
            int r = wm * 64 + i * 16 + lr;
            int c = q ^ ((r >> 1) & 3);
            af[i] = *(const bf16x8*)(&As[buf][r * 32 + c * 8]);
        }
        // swapped operands: lane holds C row m=lr, cols n = q*4 + reg
#pragma unroll
        for (int i = 0; i < 4; ++i)
#pragma unroll
            for (int j = 0; j < 2; ++j)
                acc[i][j] = __builtin_amdgcn_mfma_f32_16x16x32_bf16(
                    bfr[j], af[i], acc[i][j], 0, 0, 0);
    };

    const int nk = K >> 5;                 // 32 or 128
    stage(0, 0);                           // 2 outstanding
    int cur = 0;
    for (int t = 0; t < nk; ++t) {
        if (t + 1 < nk) {
            stage((t + 1) << 5, cur ^ 1);  // 4 outstanding
            asm volatile("s_waitcnt vmcnt(2)" ::: "memory");  // tile t landed
        } else {
            asm volatile("s_waitcnt vmcnt(0)" ::: "memory");
        }
        __builtin_amdgcn_s_barrier();      // all waves see tile t in LDS
        compute(cur);                      // compiler inserts lgkmcnt waits
        __builtin_amdgcn_s_barrier();      // done reading buf before overwrite
        cur ^= 1;
    }

    // epilogue (swapped layout): acc[mi][nj][r] = C[rowb+mi*16][colb+nj*16+r]
    int colb = n0 + wn * 32 + q * 4;
    int rowb = m0 + wm * 64 + lr;
    float4 bz[2];
#pragma unroll
    for (int nj = 0; nj < 2; ++nj)
        bz[nj] = *(const float4*)(bias + colb + nj * 16);
#pragma unroll
    for (int mi = 0; mi < 4; ++mi) {
        int row = rowb + mi * 16;
#pragma unroll
        for (int nj = 0; nj < 2; ++nj) {
            float v0 = acc[mi][nj][0] + bz[nj].x;
            float v1 = acc[mi][nj][1] + bz[nj].y;
            float v2 = acc[mi][nj][2] + bz[nj].z;
            float v3 = acc[mi][nj][3] + bz[nj].w;
            if (ACT_GELU) {
                v0 = gelu_fast(v0); v1 = gelu_fast(v1);
                v2 = gelu_fast(v2); v3 = gelu_fast(v3);
            }
            int col = colb + nj * 16;
            if (!FFN2 || e < NEXP) {
                uint2 u;
                u.x = (unsigned)f2b(v0) | ((unsigned)f2b(v1) << 16);
                u.y = (unsigned)f2b(v2) | ((unsigned)f2b(v3) << 16);
                *(uint2*)(Cb + (size_t)row * N + col) = u;
            } else {
                float4 f = make_float4(v0, v1, v2, v3);
                *(float4*)(Cf + (size_t)(row - SLOT_PAD) * N + col) = f;
            }
        }
    }
}

// ------------------------------- combine -----------------------------------
__global__ void combine_kernel(float* __restrict__ out, const ushort_t* __restrict__ OutS,
                               const int* __restrict__ slot_of, const float* __restrict__ tw) {
    int t = blockIdx.x;
    int d = threadIdx.x * 4;
    int s0 = slot_of[2 * t], s1 = slot_of[2 * t + 1];
    float w0 = tw[2 * t], w1 = tw[2 * t + 1];
    float* po = out + (size_t)t * DDIM + d;
    float4 o = *(float4*)po;
    const ushort_t* p0 = OutS + (size_t)s0 * DDIM + d;
    const ushort_t* p1 = OutS + (size_t)s1 * DDIM + d;
    o.x += w0 * b2f(p0[0]) + w1 * b2f(p1[0]);
    o.y += w0 * b2f(p0[1]) + w1 * b2f(p1[1]);
    o.z += w0 * b2f(p0[2]) + w1 * b2f(p1[2]);
    o.w += w0 * b2f(p0[3]) + w1 * b2f(p1[3]);
    *(float4*)po = o;
}

// ------------------------------- launch ------------------------------------
extern "C" void kernel_launch(void* const* d_in, const int* in_sizes, int n_in,
                              void* d_out, int out_size, void* d_ws, size_t ws_size,
                              hipStream_t stream) {
    const float* x      = (const float*)d_in[0];
    const float* gw     = (const float*)d_in[1];
    const float* w_in   = (const float*)d_in[2];
    const float* b_in   = (const float*)d_in[3];
    const float* w_out  = (const float*)d_in[4];
    const float* b_out  = (const float*)d_in[5];
    const float* sw_in  = (const float*)d_in[6];
    const float* sb_in  = (const float*)d_in[7];
    const float* sw_out = (const float*)d_in[8];
    const float* sb_out = (const float*)d_in[9];
    float* out = (float*)d_out;

    char* ws = (char*)d_ws;
    int*      cnt     = (int*)(ws + OFF_CNT);      // [0..7]=cnt, [8..15]=cur
    int*      offs    = (int*)(ws + OFF_OFFS);
    int*      tidx    = (int*)(ws + OFF_TIDX);
    float*    tw      = (float*)(ws + OFF_TW);
    int*      slot_of = (int*)(ws + OFF_SLOT);
    int*      tok_of  = (int*)(ws + OFF_TOK);
    ushort_t* Xall    = (ushort_t*)(ws + OFF_XALL);
    ushort_t* OutS    = (ushort_t*)(ws + OFF_OUTS); // aliases Xall (used after GEMM1)
    ushort_t* Wt      = (ushort_t*)(ws + OFF_WT);   // [9][N][K], FFN1 then FFN2
    ushort_t* Hbuf    = (ushort_t*)(ws + OFF_H);    // bf16 [14336][4096]

    // routing (cnt+cur zeroed by async memset; no tok_of init needed)
    hipMemsetAsync(cnt, 0, 64, stream);
    gate_kernel<<<T_TOK, 64, 0, stream>>>(x, gw, tidx, tw, cnt);
    assign_kernel<<<(2 * T_TOK + 255) / 256, 256, 0, stream>>>(tidx, cnt, cnt + 8,
                                                               offs, slot_of, tok_of);
    build_x<<<M_ALL, 256, 0, stream>>>(x, tok_of, offs, cnt, Xall);

    // FFN1 weights: [9][4096][1024] bf16 (w_in experts + sw_in as expert 8)
    transpose_cvt9<<<dim3(DDIM / 64, HDIM / 64, NEXP + 1), 256, 0, stream>>>(
        w_in, sw_in, Wt, DDIM, HDIM);
    // H = gelu(Xall @ W1 + b1)
    gemm_moe<true, false><<<dim3(M_ALL / 128, HDIM / 128), 512, 0, stream>>>(
        Xall, Wt, b_in, sb_in, Hbuf, nullptr, offs, HDIM, DDIM);

    // FFN2 weights: [9][1024][4096] bf16
    transpose_cvt9<<<dim3(HDIM / 64, DDIM / 64, NEXP + 1), 256, 0, stream>>>(
        w_out, sw_out, Wt, HDIM, DDIM);
    // expert rows -> OutS (bf16); shared rows -> out (fp32, includes bias)
    gemm_moe<false, true><<<dim3(M_ALL / 128, DDIM / 128), 512, 0, stream>>>(
        Hbuf, Wt, b_out, sb_out, OutS, out, offs, DDIM, HDIM);

    // out += w0*OutS[slot0] + w1*OutS[slot1]
    combine_kernel<<<T_TOK, 256, 0, stream>>>(out, OutS, slot_of, tw);
    (void)in_sizes; (void)n_in; (void)out_size; (void)ws_size;
}

// Round 13
// 555.977 us; speedup vs baseline: 1.0158x; 1.0158x over previous
//
#include <hip/hip_runtime.h>
#include <hip/hip_bf16.h>
#include <math.h>

// ---------------------------------------------------------------------------
// MoE block: y = sum_topk2 w_e * FFN_e(x)  +  FFN_shared(x)
// T=4096, D=1024, H=4096, E=8, K=2.  bf16 MFMA compute.
// R13: R12 GEMM (128x128, BK=32, 8 waves, 32KB LDS, 4 blk/CU = 8 waves/SIMD,
// counted vmcnt(2), swapped-operand MFMA, vectorized epilogue) kept intact.
// Cuts: 128-aligned expert padding (matches M-tile, ~4% less GEMM work),
// ushort2-vectorized transpose writes, gate emits shared bf16 rows.
// ---------------------------------------------------------------------------

typedef unsigned short ushort_t;
typedef __attribute__((ext_vector_type(8))) __bf16 bf16x8;
typedef __attribute__((ext_vector_type(4))) float f32x4;

#define T_TOK 4096
#define DDIM  1024
#define HDIM  4096
#define NEXP  8
#define SLOT_PAD 9216            // 8192 + 8*128 pad headroom (128-aligned regions)
#define M_ALL (SLOT_PAD + T_TOK) // 13312 rows: experts then shared

// workspace layout (bytes)
#define OFF_CNT   0u             // int[8] cnt + int[8] cur
#define OFF_OFFS  64u            // int[16]
#define OFF_TIDX  256u           // int[8192]
#define OFF_TW    33024u         // float[8192]
#define OFF_SLOT  65792u         // int[8192]
#define OFF_TOK   98560u         // int[9216]
#define OFF_XALL  1048576u                        // bf16 [13312][1024] = 27,262,976
#define OFF_OUTS  OFF_XALL                        // bf16 [9216][1024] (aliases Xall)
#define OFF_WT    (OFF_XALL + 27262976u)          // bf16 [9][N][K] = 75,497,472
#define OFF_H     (OFF_WT + 75497472u)            // bf16 [13312][4096] = 109,051,904

__device__ __forceinline__ ushort_t f2b(float f) {
    __hip_bfloat16 h = __float2bfloat16(f);
    return *reinterpret_cast<ushort_t*>(&h);
}
__device__ __forceinline__ float b2f(ushort_t u) {
    __hip_bfloat16 h;
    *reinterpret_cast<ushort_t*>(&h) = u;
    return __bfloat162float(h);
}
// tanh-form GELU (max |dev| from exact erf-GELU ~3e-3; bf16-safe here)
__device__ __forceinline__ float gelu_fast(float v) {
    float u = 0.7978845608f * v * (1.0f + 0.044715f * v * v);
    float t = 1.0f - 2.0f / (__expf(2.0f * u) + 1.0f);
    return 0.5f * v * (1.0f + t);
}

// -------------------------------- gate -------------------------------------
// Also converts the token's x row to bf16 into the shared region of Xall
// (row SLOT_PAD + t) — the row is already being read here.
__global__ void gate_kernel(const float* __restrict__ x, const float* __restrict__ gw,
                            int* __restrict__ tidx, float* __restrict__ tw,
                            int* __restrict__ cnt, ushort_t* __restrict__ Xall) {
    int t = blockIdx.x;
    int l = threadIdx.x;
    ushort_t* xs = Xall + (size_t)(SLOT_PAD + t) * DDIM;
    float acc[NEXP];
#pragma unroll
    for (int e = 0; e < NEXP; ++e) acc[e] = 0.f;
    for (int i = 0; i < DDIM / 64; ++i) {
        float xi = x[(size_t)t * DDIM + i * 64 + l];
        xs[i * 64 + l] = f2b(xi);
#pragma unroll
        for (int e = 0; e < NEXP; ++e)
            acc[e] += xi * gw[e * DDIM + i * 64 + l];
    }
#pragma unroll
    for (int e = 0; e < NEXP; ++e)
        for (int off = 32; off; off >>= 1) acc[e] += __shfl_xor(acc[e], off);
    if (l == 0) {
        float m = acc[0];
#pragma unroll
        for (int e = 1; e < NEXP; ++e) m = fmaxf(m, acc[e]);
        float ex[NEXP], Z = 0.f;
#pragma unroll
        for (int e = 0; e < NEXP; ++e) { ex[e] = __expf(acc[e] - m); Z += ex[e]; }
        int b0 = 0;
#pragma unroll
        for (int e = 1; e < NEXP; ++e) if (ex[e] > ex[b0]) b0 = e;
        int b1 = (b0 == 0) ? 1 : 0;
#pragma unroll
        for (int e = 0; e < NEXP; ++e) if (e != b0 && ex[e] > ex[b1]) b1 = e;
        float inv = 1.0f / Z;
        tidx[2 * t] = b0; tidx[2 * t + 1] = b1;
        tw[2 * t] = ex[b0] * inv; tw[2 * t + 1] = ex[b1] * inv;
        atomicAdd(&cnt[b0], 1);
        atomicAdd(&cnt[b1], 1);
    }
}

// ------------------------- assign (+ offs, merged) -------------------------
// Every block recomputes the 8-entry padded prefix from cnt (reads only);
// block 0 thread 0 publishes offs. Slot order within an expert is
// atomic-race-dependent, but the OUTPUT is permutation-invariant.
__global__ void assign_kernel(const int* __restrict__ tidx, const int* __restrict__ cnt,
                              int* __restrict__ cur, int* __restrict__ offs,
                              int* __restrict__ slot_of, int* __restrict__ tok_of) {
    int off[NEXP + 1];
    off[0] = 0;
#pragma unroll
    for (int e = 0; e < NEXP; ++e) off[e + 1] = off[e] + ((cnt[e] + 127) & ~127);
    int i = blockIdx.x * 256 + threadIdx.x;
    if (i == 0) {
#pragma unroll
        for (int e = 0; e <= NEXP; ++e) offs[e] = off[e];
    }
    if (i >= 2 * T_TOK) return;
    int e = tidx[i];
    int s = off[e] + atomicAdd(&cur[e], 1);
    slot_of[i] = s;
    tok_of[s] = i >> 1;
}

// ------------------------------- build X -----------------------------------
// Expert slots only (shared rows written by gate). Pad slots detected from
// offs+cnt (local index >= cnt[e]) — no tok_of init needed.
__global__ void build_x(const float* __restrict__ x, const int* __restrict__ tok_of,
                        const int* __restrict__ offs, const int* __restrict__ cnt,
                        ushort_t* __restrict__ Xall) {
    int b = blockIdx.x;
    int k = threadIdx.x * 4;
    if (b >= offs[NEXP]) return;
    int e = 0;
    while (offs[e + 1] <= b) e++;
    int t = (b - offs[e] < cnt[e]) ? tok_of[b] : -1;
    float4 v = make_float4(0.f, 0.f, 0.f, 0.f);
    if (t >= 0) v = *(const float4*)(x + (size_t)t * DDIM + k);
    ushort_t* p = Xall + (size_t)b * DDIM + k;
    p[0] = f2b(v.x); p[1] = f2b(v.y); p[2] = f2b(v.z); p[3] = f2b(v.w);
}

// --------------------------- transpose + cvt (9 experts) -------------------
// in [K][N] fp32 -> out [N][K] bf16 ; grid (K/64, N/64, 9); z==8 -> shared.
// Writes vectorized as ushort2 (2 k-elems/lane): wave emits 2x128B contiguous
// segments instead of 1x128B of scalar 2B stores. LDS reads 2-way (free).
__global__ void transpose_cvt9(const float* __restrict__ w, const float* __restrict__ sw,
                               ushort_t* __restrict__ out, int K, int N) {
    __shared__ float t[64][65];
    int z = blockIdx.z;
    const float* in = (z < NEXP) ? w + (size_t)z * K * N : sw;
    out += (size_t)z * K * N;
    int k0 = blockIdx.x * 64, n0 = blockIdx.y * 64;
    int c = threadIdx.x & 63, r4 = threadIdx.x >> 6;
#pragma unroll
    for (int i = 0; i < 16; ++i) {
        int r = r4 + i * 4;
        t[r][c] = in[(size_t)(k0 + r) * N + n0 + c];
    }
    __syncthreads();
    int c2 = threadIdx.x & 31;            // k-pair index
    int r8 = threadIdx.x >> 5;            // 0..7
#pragma unroll
    for (int i = 0; i < 8; ++i) {
        int r = r8 + i * 8;               // output row (n)
        ushort2 u;
        u.x = f2b(t[2 * c2][r]);
        u.y = f2b(t[2 * c2 + 1][r]);
        *(ushort2*)(out + (size_t)(n0 + r) * K + k0 + 2 * c2) = u;
    }
}

// ------------------------------ GEMM (bt) ----------------------------------
// C[M,N] = act(A[M,K] @ Bt[e][N,K]^T + bias), rows grouped by expert
// (128-aligned), expert 8 = shared. 128x128 tile, BK=32, 8 waves (512 thr,
// 2Mx4N wave grid, wave-tile 64x32, acc[4][2]), mfma(B,A) swapped operands.
// LDS: As/Bs[2][128*32] = 32 KB -> 4 blocks/CU (32 waves/CU, 8/SIMD max).
// Swizzle (rows of 32 elems = 4 chunks): chunk c = q ^ ((row>>1)&3), same
// involution on stage (pre-swizzled source) and read; reads 2-way = free.
// Sync: stage(t+1) [2 loads/thr] -> vmcnt(2) -> s_barrier -> compute ->
// s_barrier (counted form; never vmcnt(0) in-loop).
template <bool ACT_GELU, bool FFN2>
__global__ __launch_bounds__(512, 8) void gemm_moe(
    const ushort_t* __restrict__ A, const ushort_t* __restrict__ WtBase,
    const float* __restrict__ bExp, const float* __restrict__ bSh,
    ushort_t* __restrict__ Cb, float* __restrict__ Cf,
    const int* __restrict__ offs, int N, int K) {
    // ---- per-XCD patch swizzle (bijective; NM%4==0, NN%2==0) ----
    int NMt = gridDim.x, NNt = gridDim.y;
    int flat = blockIdx.y * NMt + blockIdx.x;
    int xcd = flat & 7, rank = flat >> 3;
    int PM = NMt >> 2;                    // patch rows (26)
    int PN = NNt >> 1;                    // patch cols (16 or 4)
    int pm = xcd >> 1, pn = xcd & 1;      // 4 x 2 patch grid
    int mi = pm * PM + rank / PN;
    int ni = pn * PN + rank % PN;
    int m0 = mi * 128, n0 = ni * 128;

    int e;
    if (m0 >= SLOT_PAD) {
        e = NEXP;                        // shared region
    } else {
        if (m0 >= offs[NEXP]) return;    // dead pad zone (before any barrier)
        e = 0;
        while (offs[e + 1] <= m0) e++;
    }
    const ushort_t* Bt = WtBase + (size_t)e * N * K;
    const float* bias = (e == NEXP) ? bSh : bExp + (size_t)e * N;

    __shared__ ushort_t As[2][128 * 32];   // 2 x 8 KB
    __shared__ ushort_t Bs[2][128 * 32];   // 2 x 8 KB

    int tid = threadIdx.x;
    int lane = tid & 63, wid = tid >> 6;   // 8 waves
    int wm = wid >> 2, wn = wid & 3;       // 2M x 4N wave grid
    int q = lane >> 4, lr = lane & 15;

    // staging: per operand 512 16B-chunks, 1/thread. L = tid; row = L>>2,
    // stored chunk = L&3, source chunk = (L&3) ^ ((row>>1)&3).
    int srow = tid >> 2;
    int su = ((tid & 3) ^ ((srow >> 1) & 3)) * 8;
    size_t Aoff = (size_t)(m0 + srow) * K + su;
    size_t Boff = (size_t)(n0 + srow) * K + su;
    int ldsOff = tid * 8;                  // ushort elements

    f32x4 acc[4][2];
#pragma unroll
    for (int i = 0; i < 4; ++i)
#pragma unroll
        for (int j = 0; j < 2; ++j) acc[i][j] = (f32x4)(0.f);

    auto stage = [&](int kb, int buf) {    // 2 loads per thread
        __builtin_amdgcn_global_load_lds(
            (const __attribute__((address_space(1))) void*)(A + Aoff + kb),
            (__attribute__((address_space(3))) void*)(&As[buf][ldsOff]), 16, 0, 0);
        __builtin_amdgcn_global_load_lds(
            (const __attribute__((address_space(1))) void*)(Bt + Boff + kb),
            (__attribute__((address_space(3))) void*)(&Bs[buf][ldsOff]), 16, 0, 0);
    };
    auto compute = [&](int buf) {
        bf16x8 af[4], bfr[2];
#pragma unroll
        for (int j = 0; j < 2; ++j) {
            int r = wn * 32 + j * 16 + lr;
            int c = q ^ ((r >> 1) & 3);
            bfr[j] = *(const bf16x8*)(&Bs[buf][r * 32 + c * 8]);
        }
#pragma unroll
        for (int i = 0; i < 4; ++i) {
            int r = wm * 64 + i * 16 + lr;
            int c = q ^ ((r >> 1) & 3);
            af[i] = *(const bf16x8*)(&As[buf][r * 32 + c * 8]);
        }
        // swapped operands: lane holds C row m=lr, cols n = q*4 + reg
#pragma unroll
        for (int i = 0; i < 4; ++i)
#pragma unroll
            for (int j = 0; j < 2; ++j)
                acc[i][j] = __builtin_amdgcn_mfma_f32_16x16x32_bf16(
                    bfr[j], af[i], acc[i][j], 0, 0, 0);
    };

    const int nk = K >> 5;                 // 32 or 128
    stage(0, 0);                           // 2 outstanding
    int cur = 0;
    for (int t = 0; t < nk; ++t) {
        if (t + 1 < nk) {
            stage((t + 1) << 5, cur ^ 1);  // 4 outstanding
            asm volatile("s_waitcnt vmcnt(2)" ::: "memory");  // tile t landed
        } else {
            asm volatile("s_waitcnt vmcnt(0)" ::: "memory");
        }
        __builtin_amdgcn_s_barrier();      // all waves see tile t in LDS
        compute(cur);                      // compiler inserts lgkmcnt waits
        __builtin_amdgcn_s_barrier();      // done reading buf before overwrite
        cur ^= 1;
    }

    // epilogue (swapped layout): acc[mi][nj][r] = C[rowb+mi*16][colb+nj*16+r]
    int colb = n0 + wn * 32 + q * 4;
    int rowb = m0 + wm * 64 + lr;
    float4 bz[2];
#pragma unroll
    for (int nj = 0; nj < 2; ++nj)
        bz[nj] = *(const float4*)(bias + colb + nj * 16);
#pragma unroll
    for (int mi = 0; mi < 4; ++mi) {
        int row = rowb + mi * 16;
#pragma unroll
        for (int nj = 0; nj < 2; ++nj) {
            float v0 = acc[mi][nj][0] + bz[nj].x;
            float v1 = acc[mi][nj][1] + bz[nj].y;
            float v2 = acc[mi][nj][2] + bz[nj].z;
            float v3 = acc[mi][nj][3] + bz[nj].w;
            if (ACT_GELU) {
                v0 = gelu_fast(v0); v1 = gelu_fast(v1);
                v2 = gelu_fast(v2); v3 = gelu_fast(v3);
            }
            int col = colb + nj * 16;
            if (!FFN2 || e < NEXP) {
                uint2 u;
                u.x = (unsigned)f2b(v0) | ((unsigned)f2b(v1) << 16);
                u.y = (unsigned)f2b(v2) | ((unsigned)f2b(v3) << 16);
                *(uint2*)(Cb + (size_t)row * N + col) = u;
            } else {
                float4 f = make_float4(v0, v1, v2, v3);
                *(float4*)(Cf + (size_t)(row - SLOT_PAD) * N + col) = f;
            }
        }
    }
}

// ------------------------------- combine -----------------------------------
__global__ void combine_kernel(float* __restrict__ out, const ushort_t* __restrict__ OutS,
                               const int* __restrict__ slot_of, const float* __restrict__ tw) {
    int t = blockIdx.x;
    int d = threadIdx.x * 4;
    int s0 = slot_of[2 * t], s1 = slot_of[2 * t + 1];
    float w0 = tw[2 * t], w1 = tw[2 * t + 1];
    float* po = out + (size_t)t * DDIM + d;
    float4 o = *(float4*)po;
    const ushort_t* p0 = OutS + (size_t)s0 * DDIM + d;
    const ushort_t* p1 = OutS + (size_t)s1 * DDIM + d;
    o.x += w0 * b2f(p0[0]) + w1 * b2f(p1[0]);
    o.y += w0 * b2f(p0[1]) + w1 * b2f(p1[1]);
    o.z += w0 * b2f(p0[2]) + w1 * b2f(p1[2]);
    o.w += w0 * b2f(p0[3]) + w1 * b2f(p1[3]);
    *(float4*)po = o;
}

// ------------------------------- launch ------------------------------------
extern "C" void kernel_launch(void* const* d_in, const int* in_sizes, int n_in,
                              void* d_out, int out_size, void* d_ws, size_t ws_size,
                              hipStream_t stream) {
    const float* x      = (const float*)d_in[0];
    const float* gw     = (const float*)d_in[1];
    const float* w_in   = (const float*)d_in[2];
    const float* b_in   = (const float*)d_in[3];
    const float* w_out  = (const float*)d_in[4];
    const float* b_out  = (const float*)d_in[5];
    const float* sw_in  = (const float*)d_in[6];
    const float* sb_in  = (const float*)d_in[7];
    const float* sw_out = (const float*)d_in[8];
    const float* sb_out = (const float*)d_in[9];
    float* out = (float*)d_out;

    char* ws = (char*)d_ws;
    int*      cnt     = (int*)(ws + OFF_CNT);      // [0..7]=cnt, [8..15]=cur
    int*      offs    = (int*)(ws + OFF_OFFS);
    int*      tidx    = (int*)(ws + OFF_TIDX);
    float*    tw      = (float*)(ws + OFF_TW);
    int*      slot_of = (int*)(ws + OFF_SLOT);
    int*      tok_of  = (int*)(ws + OFF_TOK);
    ushort_t* Xall    = (ushort_t*)(ws + OFF_XALL);
    ushort_t* OutS    = (ushort_t*)(ws + OFF_OUTS); // aliases Xall (used after GEMM1)
    ushort_t* Wt      = (ushort_t*)(ws + OFF_WT);   // [9][N][K], FFN1 then FFN2
    ushort_t* Hbuf    = (ushort_t*)(ws + OFF_H);    // bf16 [13312][4096]

    // routing (cnt+cur zeroed by async memset; no tok_of init needed)
    hipMemsetAsync(cnt, 0, 64, stream);
    gate_kernel<<<T_TOK, 64, 0, stream>>>(x, gw, tidx, tw, cnt, Xall);
    assign_kernel<<<(2 * T_TOK + 255) / 256, 256, 0, stream>>>(tidx, cnt, cnt + 8,
                                                               offs, slot_of, tok_of);
    build_x<<<SLOT_PAD, 256, 0, stream>>>(x, tok_of, offs, cnt, Xall);

    // FFN1 weights: [9][4096][1024] bf16 (w_in experts + sw_in as expert 8)
    transpose_cvt9<<<dim3(DDIM / 64, HDIM / 64, NEXP + 1), 256, 0, stream>>>(
        w_in, sw_in, Wt, DDIM, HDIM);
    // H = gelu(Xall @ W1 + b1)
    gemm_moe<true, false><<<dim3(M_ALL / 128, HDIM / 128), 512, 0, stream>>>(
        Xall, Wt, b_in, sb_in, Hbuf, nullptr, offs, HDIM, DDIM);

    // FFN2 weights: [9][1024][4096] bf16
    transpose_cvt9<<<dim3(HDIM / 64, DDIM / 64, NEXP + 1), 256, 0, stream>>>(
        w_out, sw_out, Wt, HDIM, DDIM);
    // expert rows -> OutS (bf16); shared rows -> out (fp32, includes bias)
    gemm_moe<false, true><<<dim3(M_ALL / 128, DDIM / 128), 512, 0, stream>>>(
        Hbuf, Wt, b_out, sb_out, OutS, out, offs, DDIM, HDIM);

    // out += w0*OutS[slot0] + w1*OutS[slot1]
    combine_kernel<<<T_TOK, 256, 0, stream>>>(out, OutS, slot_of, tw);
    (void)in_sizes; (void)n_in; (void)out_size; (void)ws_size;
}